// Round 7
// baseline (151.880 us; speedup 1.0000x reference)
//
#include <hip/hip_runtime.h>
#include <math.h>

// ---------------------------------------------------------------------------
// MutilLocalLoss on MI355X.
// Level constants (match Python int()/round() semantics exactly):
//   lev: C,  A,  CROP, TOP, OH(=OW), NSJ, NS,  CSPLIT, RSPLIT, CHUNKS, START
//   0:   64, 16,  6,    5,  11,      3,   33,  4,      1,      1,      0
//   1:   32, 32, 13,   10,  20,      5,  100,  2,      4,      2,      968
//   2:   16, 64, 26,   19,  39,     10,  390,  4,      4,      7,      4168
//   3:    8,128, 53,   38,  76,     19, 1444,  8,      4,     23,      16336
// R3: prep 266µs latency-bound -> split/vectorized (311->181µs).
// R4: corr 174µs latency-bound (1.1 waves/SIMD) -> 6944 waves + atomics (153µs).
// R5: float4 reg-buffer rows -> VGPR 96->52 but NEUTRAL (VALUBusy still 24%):
//     64-thread blocks hit the 16-workgroup/CU cap = 50% occupancy ceiling;
//     2.8 resident waves/SIMD x ~20% per-wave duty = the 24% we measured.
// R6: 256-thread corr blocks: 4 work-items/block (one per wave), per-wave
//     g_lds slice (4x896 floats). 1736 blocks; residency cap -> 32 waves/CU.
// ws floats: [0,32) sc; [32, 32+62544) corr accum; [62576, +1024) prep parts.
// ---------------------------------------------------------------------------

#define WS_SC 0
#define WS_CORR 32
#define WS_PART (32 + 62544)
#define N_ENTRIES 62544

__device__ __forceinline__ float block_sum256(float v, float* sw) {
#pragma unroll
  for (int o = 32; o > 0; o >>= 1) v += __shfl_down(v, o, 64);
  if ((threadIdx.x & 63) == 0) sw[threadIdx.x >> 6] = v;
  __syncthreads();
  float r = (threadIdx.x < 4) ? sw[threadIdx.x] : 0.0f;
  r += __shfl_down(r, 2, 64);
  r += __shfl_down(r, 1, 64);
  __syncthreads();
  return r;  // total valid in thread 0
}

// ---------------- init: zero corr accumulators + out ------------------------
__global__ __launch_bounds__(256) void init_kernel(float* __restrict__ ws,
                                                   float* __restrict__ out) {
  const int e = blockIdx.x * 256 + threadIdx.x;
  if (e < N_ENTRIES) ws[WS_CORR + e] = 0.0f;
  if (e == 0) out[0] = 0.0f;
}

// ---------------- prep stage 1: 16-way sliced partial energies --------------
template <int C, int A, int CROP, int TOP>
__device__ void prep_partial_level(const float* __restrict__ grd,
                                   const float* __restrict__ sat,
                                   const float* __restrict__ mask, int b, int k,
                                   float* __restrict__ part, float* sw) {
  const float* gb = grd + (size_t)b * C * A * A;
  float s1 = 0.0f;
  constexpr int N1 = C * CROP * CROP;
  for (int idx = k * 256 + (int)threadIdx.x; idx < N1; idx += 4096) {
    int c = idx / (CROP * CROP);
    int r = idx - c * (CROP * CROP);
    int h = r / CROP;
    int w = r - h * CROP;
    float m = mask[(TOP + h) * A + (TOP + w)];
    float g = gb[((size_t)c * A + (TOP + h)) * A + (TOP + w)] * m;
    s1 += g * g;
  }
  s1 = block_sum256(s1, sw);
  const float4* sb = (const float4*)(sat + (size_t)b * C * A * A);
  const float4* m4 = (const float4*)mask;
  float s2 = 0.0f;
  constexpr int NV = C * A * A / 4;
  constexpr int MV = A * A / 4;
  for (int v = k * 256 + (int)threadIdx.x; v < NV; v += 4096) {
    float4 sv = sb[v];
    float4 mv = m4[v & (MV - 1)];
    s2 += sv.x * sv.x * mv.x + sv.y * sv.y * mv.y + sv.z * sv.z * mv.z +
          sv.w * sv.w * mv.w;
  }
  s2 = block_sum256(s2, sw);
  if (threadIdx.x == 0) {
    part[0] = s1;
    part[1] = s2;
  }
}

__global__ __launch_bounds__(256) void prep_partial_kernel(
    const float* g0, const float* s0, const float* m0, const float* g1,
    const float* s1, const float* m1, const float* g2, const float* s2,
    const float* m2, const float* g3, const float* s3, const float* m3,
    float* ws) {
  __shared__ float sw[4];
  const int pair = blockIdx.x >> 4;   // 0..31
  const int k = blockIdx.x & 15;      // slice 0..15
  const int lev = pair >> 3;
  const int b = pair & 7;
  float* part = ws + WS_PART + (pair * 16 + k) * 2;
  if (lev == 0)      prep_partial_level<64, 16, 6, 5>(g0, s0, m0, b, k, part, sw);
  else if (lev == 1) prep_partial_level<32, 32, 13, 10>(g1, s1, m1, b, k, part, sw);
  else if (lev == 2) prep_partial_level<16, 64, 26, 19>(g2, s2, m2, b, k, part, sw);
  else               prep_partial_level<8, 128, 53, 38>(g3, s3, m3, b, k, part, sw);
}

// ---------------- prep stage 2: finalize scale factors ----------------------
__global__ __launch_bounds__(64) void prep_final_kernel(float* __restrict__ ws) {
  const int t = threadIdx.x;
  if (t < 32) {
    float s1 = 0.0f, s2 = 0.0f;
    const float* p = ws + WS_PART + t * 32;
    for (int k = 0; k < 16; ++k) {
      s1 += p[2 * k];
      s2 += p[2 * k + 1];
    }
    float norm = sqrtf(s1);
    float denom = fmaxf(sqrtf(s2 + 1e-8f), 1e-6f);
    ws[WS_SC + t] = 2.0f / (fmaxf(norm, 1e-12f) * denom);
  }
}

// ---------------- corr: raw correlation partials (atomic accumulate) --------
// Row kernel: load the thread's sat row span as float4s into a fully-static
// register buffer (independent loads -> deep MLP), then 4-output FMA sweep.
template <int CROP, int NV4>
__device__ __forceinline__ void dot_row_vec(const float* __restrict__ srow,
                                            int lastoff,
                                            const float* __restrict__ grow,
                                            float acc[4]) {
  float rbuf[NV4 * 4];
#pragma unroll
  for (int k = 0; k < NV4 - 1; ++k) {
    float4 t = *(const float4*)(srow + 4 * k);
    rbuf[4 * k + 0] = t.x;
    rbuf[4 * k + 1] = t.y;
    rbuf[4 * k + 2] = t.z;
    rbuf[4 * k + 3] = t.w;
  }
  {
    float4 t = *(const float4*)(srow + lastoff);  // clamped: may duplicate
    rbuf[4 * (NV4 - 1) + 0] = t.x;
    rbuf[4 * (NV4 - 1) + 1] = t.y;
    rbuf[4 * (NV4 - 1) + 2] = t.z;
    rbuf[4 * (NV4 - 1) + 3] = t.w;
  }
#pragma unroll
  for (int w = 0; w < CROP; ++w) {
    const float g = grow[w];
    acc[0] = fmaf(rbuf[w + 0], g, acc[0]);
    acc[1] = fmaf(rbuf[w + 1], g, acc[1]);
    acc[2] = fmaf(rbuf[w + 2], g, acc[2]);
    acc[3] = fmaf(rbuf[w + 3], g, acc[3]);
  }
}

template <int C, int A, int CROP, int TOP, int OH, int NSJ, int CSPLIT,
          int RSPLIT, int CHUNKS, int START>
__device__ void corr_level(int rel, int lane, const float* __restrict__ grd,
                           const float* __restrict__ sat,
                           const float* __restrict__ mask,
                           float* __restrict__ ws, float* g_lds) {
  constexpr int CSP = C / CSPLIT;
  constexpr int NS = NSJ * OH;
  constexpr int OW = OH;
  constexpr int NV4 = (CROP + 3 + 3) / 4;  // ceil((CROP+3)/4) float4 per row
  constexpr int perb = CSPLIT * RSPLIT * CHUNKS;
  const int b = rel / perb;
  int r2 = rel - b * perb;
  const int cs = r2 / (RSPLIT * CHUNKS);
  r2 -= cs * (RSPLIT * CHUNKS);
  const int rs = r2 / CHUNKS;
  const int chunk = r2 - rs * CHUNKS;
  const int c0 = cs * CSP;
  const int r0 = (rs * CROP) / RSPLIT;       // filter-row slice [r0, r1)
  const int r1 = ((rs + 1) * CROP) / RSPLIT;
  const int nr = r1 - r0;

  // stage this wave's masked grd row-slice into its LDS slice (<= 832 floats)
  const float* gb = grd + (size_t)(b * C + c0) * A * A;
  const int GN = CSP * nr * CROP;
  for (int idx = lane; idx < GN; idx += 64) {
    int c = idx / (nr * CROP);
    int rem = idx - c * (nr * CROP);
    int h = rem / CROP;
    int w = rem - h * CROP;
    g_lds[idx] = gb[((size_t)c * A + (TOP + r0 + h)) * A + (TOP + w)] *
                 mask[(TOP + r0 + h) * A + (TOP + w)];
  }
  __syncthreads();

  const int s = chunk * 64 + lane;
  const bool active = s < NS;
  const int ss = active ? s : 0;
  const int i = ss / NSJ;
  const int j0 = (ss - i * NSJ) * 4;            // always 16B-aligned
  const int lastoff = min(4 * (NV4 - 1), A - 4 - j0);  // clamp final float4

  float acc[4] = {0.f, 0.f, 0.f, 0.f};
  const float* sb =
      sat + (size_t)(b * C + c0) * A * A + (size_t)(i + r0) * A + j0;
#pragma unroll 1
  for (int c = 0; c < CSP; ++c) {
    const float* satc = sb + (size_t)c * A * A;
    const float* gl = g_lds + c * nr * CROP;
#pragma unroll 1
    for (int h = 0; h < nr; ++h) {
      dot_row_vec<CROP, NV4>(satc + h * A, lastoff, gl + h * CROP, acc);
    }
  }
  if (active) {
    float* dst = ws + WS_CORR + START + (b * OH + i) * OW + j0;
#pragma unroll
    for (int t = 0; t < 4; ++t)
      if (j0 + t < OW) atomicAdd(dst + t, acc[t]);
  }
}

// 4 work-items per 256-thread block: wave w handles item bid*4+w with its own
// 896-float LDS slice. Item counts per level (32/128/896/5888) are all %4==0.
__global__ __launch_bounds__(256) void corr_kernel(
    const float* g0, const float* s0, const float* m0, const float* g1,
    const float* s1, const float* m1, const float* g2, const float* s2,
    const float* m2, const float* g3, const float* s3, const float* m3,
    float* ws) {
  __shared__ float g_lds[4 * 896];
  const int wv = threadIdx.x >> 6;
  const int lane = threadIdx.x & 63;
  float* gl = g_lds + wv * 896;
  const int bid = blockIdx.x;
  if (bid < 8)
    corr_level<64, 16, 6, 5, 11, 3, 4, 1, 1, 0>(bid * 4 + wv, lane, g0, s0, m0,
                                                ws, gl);
  else if (bid < 40)
    corr_level<32, 32, 13, 10, 20, 5, 2, 4, 2, 968>((bid - 8) * 4 + wv, lane,
                                                    g1, s1, m1, ws, gl);
  else if (bid < 264)
    corr_level<16, 64, 26, 19, 39, 10, 4, 4, 7, 4168>((bid - 40) * 4 + wv, lane,
                                                      g2, s2, m2, ws, gl);
  else
    corr_level<8, 128, 53, 38, 76, 19, 8, 4, 23, 16336>(
        (bid - 264) * 4 + wv, lane, g3, s3, m3, ws, gl);
}

// ---------------- loss: softplus contrast + scalar reduction ----------------
__global__ __launch_bounds__(256) void loss_kernel(const float* __restrict__ u,
                                                   const float* __restrict__ v,
                                                   const float* __restrict__ hd,
                                                   const float* __restrict__ ws,
                                                   float* __restrict__ out) {
  __shared__ float sw[4];
  const int e = blockIdx.x * 256 + threadIdx.x;
  float term = 0.0f;
  if (e < N_ENTRIES) {
    int lev, start, OH;
    float mpp;
    if (e < 968)        { lev = 0; start = 0;     OH = 11; mpp = 6.4f; }
    else if (e < 4168)  { lev = 1; start = 968;   OH = 20; mpp = 3.2f; }
    else if (e < 16336) { lev = 2; start = 4168;  OH = 39; mpp = 1.6f; }
    else                { lev = 3; start = 16336; OH = 76; mpp = 0.8f; }
    const int r = e - start;
    const int ow2 = OH * OH;
    const int b = r / ow2;
    const float scv = ws[WS_SC + lev * 8 + b];
    // gt position, replicating the reference fp32 op order
    float t = hd[b] * 10.0f;
    t = t / 180.0f;
    t = t * 3.14159265358979323846f;
    const float cs = cosf(t), sn = sinf(t);
    const float gdx = -u[b] * 20.0f;
    const float gdy = -v[b] * 20.0f;
    const float dxr = -gdx * cs + gdy * sn;
    const float dyr = gdx * sn + gdy * cs;
    int wi = (int)rintf(OH * 0.5f - 0.5f + dxr / mpp);  // rintf = round-half-even
    int hi = (int)rintf(OH * 0.5f - 0.5f + dyr / mpp);
    wi = min(max(wi, 0), OH - 1);
    hi = min(max(hi, 0), OH - 1);
    const float raw = ws[WS_CORR + e];
    const float rp = ws[WS_CORR + start + (b * OH + hi) * OH + wi];
    // pos - corr = sc * (raw_entry - raw_pos);  logaddexp(0, 10*(pos-corr))
    const float z = 10.0f * scv * (raw - rp);
    const float spl = fmaxf(z, 0.0f) + log1pf(expf(-fabsf(z)));
    term = spl / (8.0f * (float)(ow2 - 1));
  }
  const float tot = block_sum256(term, sw);
  if (threadIdx.x == 0) atomicAdd(out, tot);
}

// ---------------------------------------------------------------------------
extern "C" void kernel_launch(void* const* d_in, const int* in_sizes, int n_in,
                              void* d_out, int out_size, void* d_ws,
                              size_t ws_size, hipStream_t stream) {
  const float* g0 = (const float*)d_in[0];
  const float* s0 = (const float*)d_in[1];
  const float* m0 = (const float*)d_in[2];
  const float* g1 = (const float*)d_in[3];
  const float* s1 = (const float*)d_in[4];
  const float* m1 = (const float*)d_in[5];
  const float* g2 = (const float*)d_in[6];
  const float* s2 = (const float*)d_in[7];
  const float* m2 = (const float*)d_in[8];
  const float* g3 = (const float*)d_in[9];
  const float* s3 = (const float*)d_in[10];
  const float* m3 = (const float*)d_in[11];
  const float* u  = (const float*)d_in[12];
  const float* v  = (const float*)d_in[13];
  const float* hd = (const float*)d_in[14];
  float* ws = (float*)d_ws;
  float* out = (float*)d_out;

  init_kernel<<<dim3(245), dim3(256), 0, stream>>>(ws, out);
  prep_partial_kernel<<<dim3(512), dim3(256), 0, stream>>>(
      g0, s0, m0, g1, s1, m1, g2, s2, m2, g3, s3, m3, ws);
  prep_final_kernel<<<dim3(1), dim3(64), 0, stream>>>(ws);
  corr_kernel<<<dim3(1736), dim3(256), 0, stream>>>(g0, s0, m0, g1, s1, m1, g2,
                                                    s2, m2, g3, s3, m3, ws);
  loss_kernel<<<dim3(245), dim3(256), 0, stream>>>(u, v, hd, ws, out);
}

// Round 8
// 127.775 us; speedup vs baseline: 1.1886x; 1.1886x over previous
//
#include <hip/hip_runtime.h>
#include <math.h>

// ---------------------------------------------------------------------------
// MutilLocalLoss on MI355X.
// Level constants (match Python int()/round() semantics exactly):
//   lev: C,  A,  CROP, TOP, OH, TJ, NTILES, CSPLIT, RSPLIT, CHUNKS, START, perb
//   0:   64, 16,  6,    5,  11,  3,   9,     8,      1,      1,      0,     8
//   1:   32, 32, 13,   10,  20,  5,  25,    16,      1,      1,    968,    16
//   2:   16, 64, 26,   19,  39, 10, 100,     8,      4,      2,   4168,    64
//   3:    8,128, 53,   38,  76, 19, 361,     8,      8,      6,  16336,   384
// R3: prep 266µs latency-bound -> split/vectorized (311->181µs).
// R4: corr 174µs -> 6944 waves + atomic accumulation (153µs).
// R5/R6/R7: VALUBusy pinned at 24% regardless of ILP/occupancy changes ->
//     the cap is vector-memory: 1 float4 load per 15 FMA, ~14x redundancy,
//     ~1.3GB L1-side traffic (demand ~264 B/cy/CU vs ~64 served = 0.24 ✓).
// R8: 4x4 output tile per thread: each loaded sat row feeds 4 filter rows,
//     each LDS filter broadcast feeds 16 FMA. Loads 4x down. Exactly-once
//     atomics via dual ownership masks (row+col clamp).
// ws floats: [0,32) sc; [32, 32+62544) corr accum; [62576, +1024) prep parts.
// ---------------------------------------------------------------------------

#define WS_SC 0
#define WS_CORR 32
#define WS_PART (32 + 62544)
#define N_ENTRIES 62544

__device__ __forceinline__ float block_sum256(float v, float* sw) {
#pragma unroll
  for (int o = 32; o > 0; o >>= 1) v += __shfl_down(v, o, 64);
  if ((threadIdx.x & 63) == 0) sw[threadIdx.x >> 6] = v;
  __syncthreads();
  float r = (threadIdx.x < 4) ? sw[threadIdx.x] : 0.0f;
  r += __shfl_down(r, 2, 64);
  r += __shfl_down(r, 1, 64);
  __syncthreads();
  return r;  // total valid in thread 0
}

// ---------------- init: zero corr accumulators + out ------------------------
__global__ __launch_bounds__(256) void init_kernel(float* __restrict__ ws,
                                                   float* __restrict__ out) {
  const int e = blockIdx.x * 256 + threadIdx.x;
  if (e < N_ENTRIES) ws[WS_CORR + e] = 0.0f;
  if (e == 0) out[0] = 0.0f;
}

// ---------------- prep stage 1: 16-way sliced partial energies --------------
template <int C, int A, int CROP, int TOP>
__device__ void prep_partial_level(const float* __restrict__ grd,
                                   const float* __restrict__ sat,
                                   const float* __restrict__ mask, int b, int k,
                                   float* __restrict__ part, float* sw) {
  const float* gb = grd + (size_t)b * C * A * A;
  float s1 = 0.0f;
  constexpr int N1 = C * CROP * CROP;
  for (int idx = k * 256 + (int)threadIdx.x; idx < N1; idx += 4096) {
    int c = idx / (CROP * CROP);
    int r = idx - c * (CROP * CROP);
    int h = r / CROP;
    int w = r - h * CROP;
    float m = mask[(TOP + h) * A + (TOP + w)];
    float g = gb[((size_t)c * A + (TOP + h)) * A + (TOP + w)] * m;
    s1 += g * g;
  }
  s1 = block_sum256(s1, sw);
  const float4* sb = (const float4*)(sat + (size_t)b * C * A * A);
  const float4* m4 = (const float4*)mask;
  float s2 = 0.0f;
  constexpr int NV = C * A * A / 4;
  constexpr int MV = A * A / 4;
  for (int v = k * 256 + (int)threadIdx.x; v < NV; v += 4096) {
    float4 sv = sb[v];
    float4 mv = m4[v & (MV - 1)];
    s2 += sv.x * sv.x * mv.x + sv.y * sv.y * mv.y + sv.z * sv.z * mv.z +
          sv.w * sv.w * mv.w;
  }
  s2 = block_sum256(s2, sw);
  if (threadIdx.x == 0) {
    part[0] = s1;
    part[1] = s2;
  }
}

__global__ __launch_bounds__(256) void prep_partial_kernel(
    const float* g0, const float* s0, const float* m0, const float* g1,
    const float* s1, const float* m1, const float* g2, const float* s2,
    const float* m2, const float* g3, const float* s3, const float* m3,
    float* ws) {
  __shared__ float sw[4];
  const int pair = blockIdx.x >> 4;   // 0..31
  const int k = blockIdx.x & 15;      // slice 0..15
  const int lev = pair >> 3;
  const int b = pair & 7;
  float* part = ws + WS_PART + (pair * 16 + k) * 2;
  if (lev == 0)      prep_partial_level<64, 16, 6, 5>(g0, s0, m0, b, k, part, sw);
  else if (lev == 1) prep_partial_level<32, 32, 13, 10>(g1, s1, m1, b, k, part, sw);
  else if (lev == 2) prep_partial_level<16, 64, 26, 19>(g2, s2, m2, b, k, part, sw);
  else               prep_partial_level<8, 128, 53, 38>(g3, s3, m3, b, k, part, sw);
}

// ---------------- prep stage 2: finalize scale factors ----------------------
__global__ __launch_bounds__(64) void prep_final_kernel(float* __restrict__ ws) {
  const int t = threadIdx.x;
  if (t < 32) {
    float s1 = 0.0f, s2 = 0.0f;
    const float* p = ws + WS_PART + t * 32;
    for (int k = 0; k < 16; ++k) {
      s1 += p[2 * k];
      s2 += p[2 * k + 1];
    }
    float norm = sqrtf(s1);
    float denom = fmaxf(sqrtf(s2 + 1e-8f), 1e-6f);
    ws[WS_SC + t] = 2.0f / (fmaxf(norm, 1e-12f) * denom);
  }
}

// ---------------- corr: 4x4-tile correlation partials (atomic accumulate) ---
template <int C, int A, int CROP, int TOP, int OH, int TJ, int NTILES,
          int CSPLIT, int RSPLIT, int CHUNKS, int START>
__device__ void corr_level(int item, int lane, const float* __restrict__ grd,
                           const float* __restrict__ sat,
                           const float* __restrict__ mask,
                           float* __restrict__ ws, float* g_lds) {
  constexpr int CSP = C / CSPLIT;
  constexpr int OW = OH;
  constexpr int NV4 = (CROP + 3 + 3) / 4;  // ceil((CROP+3)/4) float4 per row
  constexpr int perb = CSPLIT * RSPLIT * CHUNKS;
  const int b = item / perb;
  int r2 = item - b * perb;
  const int cs = r2 / (RSPLIT * CHUNKS);
  r2 -= cs * (RSPLIT * CHUNKS);
  const int rs = r2 / CHUNKS;
  const int chunk = r2 - rs * CHUNKS;
  const int c0 = cs * CSP;
  const int r0 = (rs * CROP) / RSPLIT;       // filter-row slice [r0, r1)
  const int r1 = ((rs + 1) * CROP) / RSPLIT;
  const int nr = r1 - r0;                    // compile-time when RSPLIT==1

  // stage this wave's masked filter slice into its LDS slice (<= 371 floats)
  const float* gb = grd + (size_t)(b * C + c0) * A * A;
  for (int c = 0; c < CSP; ++c)
    for (int h = 0; h < nr; ++h)
      if (lane < CROP)
        g_lds[(c * nr + h) * CROP + lane] =
            gb[((size_t)c * A + (TOP + r0 + h)) * A + (TOP + lane)] *
            mask[(TOP + r0 + h) * A + (TOP + lane)];
  __syncthreads();

  const int s = chunk * 64 + lane;
  const bool active = s < NTILES;
  const int ss = active ? s : 0;
  const int ii = ss / TJ;
  const int jj = ss - ii * TJ;
  const int i0 = min(ii * 4, OH - 4);   // clamp; ownership masks below
  const int j0 = min(jj * 4, OW - 4);   // always 16B-aligned
  const int own_i = ii * 4 - i0;
  const int own_j = jj * 4 - j0;
  const int lastoff = min(4 * (NV4 - 1), A - 4 - j0);  // clamp final float4

  float acc[4][4] = {};
  const float* sb =
      sat + (size_t)(b * C + c0) * A * A + (size_t)(i0 + r0) * A + j0;
#pragma unroll 1
  for (int c = 0; c < CSP; ++c) {
    const float* satc = sb + (size_t)c * A * A;
    const float* gl = g_lds + c * nr * CROP;
#pragma unroll 1
    for (int r = 0; r < nr + 3; ++r) {
      // load sat row (i0+r0+r) window once; feeds up to 4 output rows
      float rbuf[NV4 * 4];
      const float* srow = satc + (size_t)r * A;
#pragma unroll
      for (int k = 0; k < NV4 - 1; ++k) {
        float4 t = *(const float4*)(srow + 4 * k);
        rbuf[4 * k + 0] = t.x;
        rbuf[4 * k + 1] = t.y;
        rbuf[4 * k + 2] = t.z;
        rbuf[4 * k + 3] = t.w;
      }
      {
        float4 t = *(const float4*)(srow + lastoff);  // clamped: may duplicate
        rbuf[4 * (NV4 - 1) + 0] = t.x;
        rbuf[4 * (NV4 - 1) + 1] = t.y;
        rbuf[4 * (NV4 - 1) + 2] = t.z;
        rbuf[4 * (NV4 - 1) + 3] = t.w;
      }
#pragma unroll
      for (int ti = 0; ti < 4; ++ti) {
        const int h = r - ti;  // filter row for output row i0+ti
        if ((unsigned)h < (unsigned)nr) {  // wave-uniform guard
          const float* grow = gl + h * CROP;
#pragma unroll
          for (int w = 0; w < CROP; ++w) {
            const float g = grow[w];
            acc[ti][0] = fmaf(rbuf[w + 0], g, acc[ti][0]);
            acc[ti][1] = fmaf(rbuf[w + 1], g, acc[ti][1]);
            acc[ti][2] = fmaf(rbuf[w + 2], g, acc[ti][2]);
            acc[ti][3] = fmaf(rbuf[w + 3], g, acc[ti][3]);
          }
        }
      }
    }
  }
  if (active) {
#pragma unroll
    for (int ti = 0; ti < 4; ++ti) {
      if (ti >= own_i) {
        float* dst = ws + WS_CORR + START + ((b * OH + i0 + ti) * OW) + j0;
#pragma unroll
        for (int tj = 0; tj < 4; ++tj)
          if (tj >= own_j) atomicAdd(dst + tj, acc[ti][tj]);
      }
    }
  }
}

// 4 work-items per 256-thread block (one per wave), per-wave LDS slice.
// Wave counts: L0 64, L1 128, L2 512, L3 3072 -> 944 blocks.
__global__ __launch_bounds__(256) void corr_kernel(
    const float* g0, const float* s0, const float* m0, const float* g1,
    const float* s1, const float* m1, const float* g2, const float* s2,
    const float* m2, const float* g3, const float* s3, const float* m3,
    float* ws) {
  __shared__ float g_lds[4 * 512];
  const int wv = threadIdx.x >> 6;
  const int lane = threadIdx.x & 63;
  float* gl = g_lds + wv * 512;
  const int bid = blockIdx.x;
  if (bid < 16)
    corr_level<64, 16, 6, 5, 11, 3, 9, 8, 1, 1, 0>(bid * 4 + wv, lane, g0, s0,
                                                   m0, ws, gl);
  else if (bid < 48)
    corr_level<32, 32, 13, 10, 20, 5, 25, 16, 1, 1, 968>((bid - 16) * 4 + wv,
                                                         lane, g1, s1, m1, ws, gl);
  else if (bid < 176)
    corr_level<16, 64, 26, 19, 39, 10, 100, 8, 4, 2, 4168>(
        (bid - 48) * 4 + wv, lane, g2, s2, m2, ws, gl);
  else
    corr_level<8, 128, 53, 38, 76, 19, 361, 8, 8, 6, 16336>(
        (bid - 176) * 4 + wv, lane, g3, s3, m3, ws, gl);
}

// ---------------- loss: softplus contrast + scalar reduction ----------------
__global__ __launch_bounds__(256) void loss_kernel(const float* __restrict__ u,
                                                   const float* __restrict__ v,
                                                   const float* __restrict__ hd,
                                                   const float* __restrict__ ws,
                                                   float* __restrict__ out) {
  __shared__ float sw[4];
  const int e = blockIdx.x * 256 + threadIdx.x;
  float term = 0.0f;
  if (e < N_ENTRIES) {
    int lev, start, OH;
    float mpp;
    if (e < 968)        { lev = 0; start = 0;     OH = 11; mpp = 6.4f; }
    else if (e < 4168)  { lev = 1; start = 968;   OH = 20; mpp = 3.2f; }
    else if (e < 16336) { lev = 2; start = 4168;  OH = 39; mpp = 1.6f; }
    else                { lev = 3; start = 16336; OH = 76; mpp = 0.8f; }
    const int r = e - start;
    const int ow2 = OH * OH;
    const int b = r / ow2;
    const float scv = ws[WS_SC + lev * 8 + b];
    // gt position, replicating the reference fp32 op order
    float t = hd[b] * 10.0f;
    t = t / 180.0f;
    t = t * 3.14159265358979323846f;
    const float cs = cosf(t), sn = sinf(t);
    const float gdx = -u[b] * 20.0f;
    const float gdy = -v[b] * 20.0f;
    const float dxr = -gdx * cs + gdy * sn;
    const float dyr = gdx * sn + gdy * cs;
    int wi = (int)rintf(OH * 0.5f - 0.5f + dxr / mpp);  // rintf = round-half-even
    int hi = (int)rintf(OH * 0.5f - 0.5f + dyr / mpp);
    wi = min(max(wi, 0), OH - 1);
    hi = min(max(hi, 0), OH - 1);
    const float raw = ws[WS_CORR + e];
    const float rp = ws[WS_CORR + start + (b * OH + hi) * OH + wi];
    // pos - corr = sc * (raw_entry - raw_pos);  logaddexp(0, 10*(pos-corr))
    const float z = 10.0f * scv * (raw - rp);
    const float spl = fmaxf(z, 0.0f) + log1pf(expf(-fabsf(z)));
    term = spl / (8.0f * (float)(ow2 - 1));
  }
  const float tot = block_sum256(term, sw);
  if (threadIdx.x == 0) atomicAdd(out, tot);
}

// ---------------------------------------------------------------------------
extern "C" void kernel_launch(void* const* d_in, const int* in_sizes, int n_in,
                              void* d_out, int out_size, void* d_ws,
                              size_t ws_size, hipStream_t stream) {
  const float* g0 = (const float*)d_in[0];
  const float* s0 = (const float*)d_in[1];
  const float* m0 = (const float*)d_in[2];
  const float* g1 = (const float*)d_in[3];
  const float* s1 = (const float*)d_in[4];
  const float* m1 = (const float*)d_in[5];
  const float* g2 = (const float*)d_in[6];
  const float* s2 = (const float*)d_in[7];
  const float* m2 = (const float*)d_in[8];
  const float* g3 = (const float*)d_in[9];
  const float* s3 = (const float*)d_in[10];
  const float* m3 = (const float*)d_in[11];
  const float* u  = (const float*)d_in[12];
  const float* v  = (const float*)d_in[13];
  const float* hd = (const float*)d_in[14];
  float* ws = (float*)d_ws;
  float* out = (float*)d_out;

  init_kernel<<<dim3(245), dim3(256), 0, stream>>>(ws, out);
  prep_partial_kernel<<<dim3(512), dim3(256), 0, stream>>>(
      g0, s0, m0, g1, s1, m1, g2, s2, m2, g3, s3, m3, ws);
  prep_final_kernel<<<dim3(1), dim3(64), 0, stream>>>(ws);
  corr_kernel<<<dim3(944), dim3(256), 0, stream>>>(g0, s0, m0, g1, s1, m1, g2,
                                                   s2, m2, g3, s3, m3, ws);
  loss_kernel<<<dim3(245), dim3(256), 0, stream>>>(u, v, hd, ws, out);
}

// Round 9
// 88.587 us; speedup vs baseline: 1.7145x; 1.4424x over previous
//
#include <hip/hip_runtime.h>
#include <math.h>

// ---------------------------------------------------------------------------
// MutilLocalLoss on MI355X.
// Level constants (match Python int()/round() semantics exactly):
//   lev: C,  A,  CROP, TOP, OH, TJ, NTILES, CSPLIT, RSPLIT, CHUNKS, START
//   0:   64, 16,  6,    5,  11,  3,   9,     8,      1,      1,      0
//   1:   32, 32, 13,   10,  20,  5,  25,    16,      1,      1,    968
//   2:   16, 64, 26,   19,  39, 10, 100,     8,      4,      2,   4168
//   3:    8,128, 53,   38,  76, 19, 361,     8,      8,      6,  16336
// R3: prep 266µs latency-bound -> split/vectorized (311->181µs).
// R4: corr 174µs -> 6944 waves + atomic accumulation (153µs).
// R5-R7: VALUBusy pinned ~24% through ILP/occupancy changes (NEUTRAL x2).
// R8: 4x4 tile/thread, loads 4x down -> only -16%; WRITE_SIZE 57MB (2x up),
//     VALUBusy still 25%. New suspect: 3.4M device-scope fp32 atomicAdds;
//     cross-XCD RMWs serialize at the memory side (64 RMW/entry at L3).
// R9: SAME grid/compute; block's 4 waves = 4 (cs,rs) slices of the SAME
//     output chunk; LDS-reduce 4 waves' acc, each wave issues 1/4 of the
//     merged atomics -> atomic count 3.4M -> 0.85M. Clean A/B on the
//     atomic-path hypothesis.
// ws floats: [0,32) sc; [32, 32+62544) corr accum; [62576, +1024) prep parts.
// ---------------------------------------------------------------------------

#define WS_SC 0
#define WS_CORR 32
#define WS_PART (32 + 62544)
#define N_ENTRIES 62544

__device__ __forceinline__ float block_sum256(float v, float* sw) {
#pragma unroll
  for (int o = 32; o > 0; o >>= 1) v += __shfl_down(v, o, 64);
  if ((threadIdx.x & 63) == 0) sw[threadIdx.x >> 6] = v;
  __syncthreads();
  float r = (threadIdx.x < 4) ? sw[threadIdx.x] : 0.0f;
  r += __shfl_down(r, 2, 64);
  r += __shfl_down(r, 1, 64);
  __syncthreads();
  return r;  // total valid in thread 0
}

// ---------------- init: zero corr accumulators + out ------------------------
__global__ __launch_bounds__(256) void init_kernel(float* __restrict__ ws,
                                                   float* __restrict__ out) {
  const int e = blockIdx.x * 256 + threadIdx.x;
  if (e < N_ENTRIES) ws[WS_CORR + e] = 0.0f;
  if (e == 0) out[0] = 0.0f;
}

// ---------------- prep stage 1: 16-way sliced partial energies --------------
template <int C, int A, int CROP, int TOP>
__device__ void prep_partial_level(const float* __restrict__ grd,
                                   const float* __restrict__ sat,
                                   const float* __restrict__ mask, int b, int k,
                                   float* __restrict__ part, float* sw) {
  const float* gb = grd + (size_t)b * C * A * A;
  float s1 = 0.0f;
  constexpr int N1 = C * CROP * CROP;
  for (int idx = k * 256 + (int)threadIdx.x; idx < N1; idx += 4096) {
    int c = idx / (CROP * CROP);
    int r = idx - c * (CROP * CROP);
    int h = r / CROP;
    int w = r - h * CROP;
    float m = mask[(TOP + h) * A + (TOP + w)];
    float g = gb[((size_t)c * A + (TOP + h)) * A + (TOP + w)] * m;
    s1 += g * g;
  }
  s1 = block_sum256(s1, sw);
  const float4* sb = (const float4*)(sat + (size_t)b * C * A * A);
  const float4* m4 = (const float4*)mask;
  float s2 = 0.0f;
  constexpr int NV = C * A * A / 4;
  constexpr int MV = A * A / 4;
  for (int v = k * 256 + (int)threadIdx.x; v < NV; v += 4096) {
    float4 sv = sb[v];
    float4 mv = m4[v & (MV - 1)];
    s2 += sv.x * sv.x * mv.x + sv.y * sv.y * mv.y + sv.z * sv.z * mv.z +
          sv.w * sv.w * mv.w;
  }
  s2 = block_sum256(s2, sw);
  if (threadIdx.x == 0) {
    part[0] = s1;
    part[1] = s2;
  }
}

__global__ __launch_bounds__(256) void prep_partial_kernel(
    const float* g0, const float* s0, const float* m0, const float* g1,
    const float* s1, const float* m1, const float* g2, const float* s2,
    const float* m2, const float* g3, const float* s3, const float* m3,
    float* ws) {
  __shared__ float sw[4];
  const int pair = blockIdx.x >> 4;   // 0..31
  const int k = blockIdx.x & 15;      // slice 0..15
  const int lev = pair >> 3;
  const int b = pair & 7;
  float* part = ws + WS_PART + (pair * 16 + k) * 2;
  if (lev == 0)      prep_partial_level<64, 16, 6, 5>(g0, s0, m0, b, k, part, sw);
  else if (lev == 1) prep_partial_level<32, 32, 13, 10>(g1, s1, m1, b, k, part, sw);
  else if (lev == 2) prep_partial_level<16, 64, 26, 19>(g2, s2, m2, b, k, part, sw);
  else               prep_partial_level<8, 128, 53, 38>(g3, s3, m3, b, k, part, sw);
}

// ---------------- prep stage 2: finalize scale factors ----------------------
__global__ __launch_bounds__(64) void prep_final_kernel(float* __restrict__ ws) {
  const int t = threadIdx.x;
  if (t < 32) {
    float s1 = 0.0f, s2 = 0.0f;
    const float* p = ws + WS_PART + t * 32;
    for (int k = 0; k < 16; ++k) {
      s1 += p[2 * k];
      s2 += p[2 * k + 1];
    }
    float norm = sqrtf(s1);
    float denom = fmaxf(sqrtf(s2 + 1e-8f), 1e-6f);
    ws[WS_SC + t] = 2.0f / (fmaxf(norm, 1e-12f) * denom);
  }
}

// ---------------- corr: 4x4-tile partials, block-reduced, 1/4 atomics -------
template <int C, int A, int CROP, int TOP, int OH, int TJ, int NTILES,
          int CSPLIT, int RSPLIT, int CHUNKS, int START>
__device__ void corr_level(int rel, int wv, int lane,
                           const float* __restrict__ grd,
                           const float* __restrict__ sat,
                           const float* __restrict__ mask,
                           float* __restrict__ ws, float* g_lds,
                           float* r_lds) {
  constexpr int CSP = C / CSPLIT;
  constexpr int OW = OH;
  constexpr int NV4 = (CROP + 3 + 3) / 4;  // ceil((CROP+3)/4) float4 per row
  constexpr int NPACK = CSPLIT * RSPLIT / 4;
  // rel -> (b, chunk, pack); wave wv covers slice pack*4+wv
  const int b = rel / (CHUNKS * NPACK);
  int r2 = rel - b * (CHUNKS * NPACK);
  const int chunk = r2 / NPACK;
  const int pack = r2 - chunk * NPACK;
  const int sl = pack * 4 + wv;
  const int cs = sl / RSPLIT;
  const int rs = sl - cs * RSPLIT;
  const int c0 = cs * CSP;
  const int r0 = (rs * CROP) / RSPLIT;       // filter-row slice [r0, r1)
  const int r1 = ((rs + 1) * CROP) / RSPLIT;
  const int nr = r1 - r0;

  // stage this wave's masked filter slice into its LDS slice (<= 371 floats)
  const float* gb = grd + (size_t)(b * C + c0) * A * A;
  for (int c = 0; c < CSP; ++c)
    for (int h = 0; h < nr; ++h)
      if (lane < CROP)
        g_lds[(c * nr + h) * CROP + lane] =
            gb[((size_t)c * A + (TOP + r0 + h)) * A + (TOP + lane)] *
            mask[(TOP + r0 + h) * A + (TOP + lane)];
  __syncthreads();

  const int s = chunk * 64 + lane;
  const bool active = s < NTILES;
  const int ss = active ? s : 0;
  const int ii = ss / TJ;
  const int jj = ss - ii * TJ;
  const int i0 = min(ii * 4, OH - 4);   // clamp; ownership masks below
  const int j0 = min(jj * 4, OW - 4);   // always 16B-aligned
  const int own_i = ii * 4 - i0;
  const int own_j = jj * 4 - j0;
  const int lastoff = min(4 * (NV4 - 1), A - 4 - j0);  // clamp final float4

  float acc[4][4] = {};
  const float* sb =
      sat + (size_t)(b * C + c0) * A * A + (size_t)(i0 + r0) * A + j0;
#pragma unroll 1
  for (int c = 0; c < CSP; ++c) {
    const float* satc = sb + (size_t)c * A * A;
    const float* gl = g_lds + c * nr * CROP;
#pragma unroll 1
    for (int r = 0; r < nr + 3; ++r) {
      // load sat row (i0+r0+r) window once; feeds up to 4 output rows
      float rbuf[NV4 * 4];
      const float* srow = satc + (size_t)r * A;
#pragma unroll
      for (int k = 0; k < NV4 - 1; ++k) {
        float4 t = *(const float4*)(srow + 4 * k);
        rbuf[4 * k + 0] = t.x;
        rbuf[4 * k + 1] = t.y;
        rbuf[4 * k + 2] = t.z;
        rbuf[4 * k + 3] = t.w;
      }
      {
        float4 t = *(const float4*)(srow + lastoff);  // clamped: may duplicate
        rbuf[4 * (NV4 - 1) + 0] = t.x;
        rbuf[4 * (NV4 - 1) + 1] = t.y;
        rbuf[4 * (NV4 - 1) + 2] = t.z;
        rbuf[4 * (NV4 - 1) + 3] = t.w;
      }
#pragma unroll
      for (int ti = 0; ti < 4; ++ti) {
        const int h = r - ti;  // filter row for output row i0+ti
        if ((unsigned)h < (unsigned)nr) {  // wave-uniform guard
          const float* grow = gl + h * CROP;
#pragma unroll
          for (int w = 0; w < CROP; ++w) {
            const float g = grow[w];
            acc[ti][0] = fmaf(rbuf[w + 0], g, acc[ti][0]);
            acc[ti][1] = fmaf(rbuf[w + 1], g, acc[ti][1]);
            acc[ti][2] = fmaf(rbuf[w + 2], g, acc[ti][2]);
            acc[ti][3] = fmaf(rbuf[w + 3], g, acc[ti][3]);
          }
        }
      }
    }
  }

  // --- block reduction: all 4 waves hold partials for the SAME tile map ---
  // r_lds layout [k][wv][lane]: b32 writes/reads, consecutive lanes -> no
  // bank conflicts.
#pragma unroll
  for (int ti = 0; ti < 4; ++ti)
#pragma unroll
    for (int tj = 0; tj < 4; ++tj)
      r_lds[((ti * 4 + tj) * 4 + wv) * 64 + lane] = acc[ti][tj];
  __syncthreads();
  // wave wv merges k = wv*4 .. wv*4+3 and issues that quarter of the atomics
#pragma unroll
  for (int kk = 0; kk < 4; ++kk) {
    const int k = wv * 4 + kk;
    const int ti = k >> 2;
    const int tj = k & 3;
    const float v = r_lds[(k * 4 + 0) * 64 + lane] +
                    r_lds[(k * 4 + 1) * 64 + lane] +
                    r_lds[(k * 4 + 2) * 64 + lane] +
                    r_lds[(k * 4 + 3) * 64 + lane];
    if (active && ti >= own_i && tj >= own_j)
      atomicAdd(ws + WS_CORR + START + ((b * OH + i0 + ti) * OW) + j0 + tj, v);
  }
}

// 4 slices per 256-thread block (one per wave) of the same output chunk.
// Blocks: L0 8*1*2=16, L1 8*1*4=32, L2 8*2*8=128, L3 8*6*16=768 -> 944.
__global__ __launch_bounds__(256) void corr_kernel(
    const float* g0, const float* s0, const float* m0, const float* g1,
    const float* s1, const float* m1, const float* g2, const float* s2,
    const float* m2, const float* g3, const float* s3, const float* m3,
    float* ws) {
  __shared__ float g_lds[4 * 512];
  __shared__ float r_lds[16 * 4 * 64];
  const int wv = threadIdx.x >> 6;
  const int lane = threadIdx.x & 63;
  float* gl = g_lds + wv * 512;
  const int bid = blockIdx.x;
  if (bid < 16)
    corr_level<64, 16, 6, 5, 11, 3, 9, 8, 1, 1, 0>(bid, wv, lane, g0, s0, m0,
                                                   ws, gl, r_lds);
  else if (bid < 48)
    corr_level<32, 32, 13, 10, 20, 5, 25, 16, 1, 1, 968>(bid - 16, wv, lane,
                                                         g1, s1, m1, ws, gl,
                                                         r_lds);
  else if (bid < 176)
    corr_level<16, 64, 26, 19, 39, 10, 100, 8, 4, 2, 4168>(
        bid - 48, wv, lane, g2, s2, m2, ws, gl, r_lds);
  else
    corr_level<8, 128, 53, 38, 76, 19, 361, 8, 8, 6, 16336>(
        bid - 176, wv, lane, g3, s3, m3, ws, gl, r_lds);
}

// ---------------- loss: softplus contrast + scalar reduction ----------------
__global__ __launch_bounds__(256) void loss_kernel(const float* __restrict__ u,
                                                   const float* __restrict__ v,
                                                   const float* __restrict__ hd,
                                                   const float* __restrict__ ws,
                                                   float* __restrict__ out) {
  __shared__ float sw[4];
  const int e = blockIdx.x * 256 + threadIdx.x;
  float term = 0.0f;
  if (e < N_ENTRIES) {
    int lev, start, OH;
    float mpp;
    if (e < 968)        { lev = 0; start = 0;     OH = 11; mpp = 6.4f; }
    else if (e < 4168)  { lev = 1; start = 968;   OH = 20; mpp = 3.2f; }
    else if (e < 16336) { lev = 2; start = 4168;  OH = 39; mpp = 1.6f; }
    else                { lev = 3; start = 16336; OH = 76; mpp = 0.8f; }
    const int r = e - start;
    const int ow2 = OH * OH;
    const int b = r / ow2;
    const float scv = ws[WS_SC + lev * 8 + b];
    // gt position, replicating the reference fp32 op order
    float t = hd[b] * 10.0f;
    t = t / 180.0f;
    t = t * 3.14159265358979323846f;
    const float cs = cosf(t), sn = sinf(t);
    const float gdx = -u[b] * 20.0f;
    const float gdy = -v[b] * 20.0f;
    const float dxr = -gdx * cs + gdy * sn;
    const float dyr = gdx * sn + gdy * cs;
    int wi = (int)rintf(OH * 0.5f - 0.5f + dxr / mpp);  // rintf = round-half-even
    int hi = (int)rintf(OH * 0.5f - 0.5f + dyr / mpp);
    wi = min(max(wi, 0), OH - 1);
    hi = min(max(hi, 0), OH - 1);
    const float raw = ws[WS_CORR + e];
    const float rp = ws[WS_CORR + start + (b * OH + hi) * OH + wi];
    // pos - corr = sc * (raw_entry - raw_pos);  logaddexp(0, 10*(pos-corr))
    const float z = 10.0f * scv * (raw - rp);
    const float spl = fmaxf(z, 0.0f) + log1pf(expf(-fabsf(z)));
    term = spl / (8.0f * (float)(ow2 - 1));
  }
  const float tot = block_sum256(term, sw);
  if (threadIdx.x == 0) atomicAdd(out, tot);
}

// ---------------------------------------------------------------------------
extern "C" void kernel_launch(void* const* d_in, const int* in_sizes, int n_in,
                              void* d_out, int out_size, void* d_ws,
                              size_t ws_size, hipStream_t stream) {
  const float* g0 = (const float*)d_in[0];
  const float* s0 = (const float*)d_in[1];
  const float* m0 = (const float*)d_in[2];
  const float* g1 = (const float*)d_in[3];
  const float* s1 = (const float*)d_in[4];
  const float* m1 = (const float*)d_in[5];
  const float* g2 = (const float*)d_in[6];
  const float* s2 = (const float*)d_in[7];
  const float* m2 = (const float*)d_in[8];
  const float* g3 = (const float*)d_in[9];
  const float* s3 = (const float*)d_in[10];
  const float* m3 = (const float*)d_in[11];
  const float* u  = (const float*)d_in[12];
  const float* v  = (const float*)d_in[13];
  const float* hd = (const float*)d_in[14];
  float* ws = (float*)d_ws;
  float* out = (float*)d_out;

  init_kernel<<<dim3(245), dim3(256), 0, stream>>>(ws, out);
  prep_partial_kernel<<<dim3(512), dim3(256), 0, stream>>>(
      g0, s0, m0, g1, s1, m1, g2, s2, m2, g3, s3, m3, ws);
  prep_final_kernel<<<dim3(1), dim3(64), 0, stream>>>(ws);
  corr_kernel<<<dim3(944), dim3(256), 0, stream>>>(g0, s0, m0, g1, s1, m1, g2,
                                                   s2, m2, g3, s3, m3, ws);
  loss_kernel<<<dim3(245), dim3(256), 0, stream>>>(u, v, hd, ws, out);
}